// Round 1
// baseline (191.009 us; speedup 1.0000x reference)
//
#include <hip/hip_runtime.h>

// CBC (classification-by-components) fused kernel.
// x:[B,1024] f32, components:[5,1024] f32, reasonings:[5,3,2] f32 -> probs:[B,3] f32.
// Memory-bound: 128 MB x-read dominates. One wave per row, components in registers.

#define DD 1024
#define KK 5
#define CC 3
#define F4_PER_ROW (DD / 4)        // 256 float4 per row
#define F4_PER_LANE (F4_PER_ROW / 64)  // 4 iterations per lane

__global__ __launch_bounds__(256) void cbc_kernel(
    const float* __restrict__ x,
    const float* __restrict__ comps,
    const float* __restrict__ reas,
    float* __restrict__ out,
    int B)
{
    const int lane = threadIdx.x & 63;
    const int waves_per_block = blockDim.x >> 6;
    const int wave_global = blockIdx.x * waves_per_block + (threadIdx.x >> 6);
    const int n_waves = gridDim.x * waves_per_block;

    // --- component fragments into registers: lane i owns float4 columns j*64+i ---
    float4 cf[KK][F4_PER_LANE];
    const float4* comps4 = (const float4*)comps;
#pragma unroll
    for (int k = 0; k < KK; ++k)
#pragma unroll
        for (int j = 0; j < F4_PER_LANE; ++j)
            cf[k][j] = comps4[k * F4_PER_ROW + j * 64 + lane];

    // --- reasoning weights (uniform scalar loads, cached; tiny) ---
    // R[k][c][0]=A, R[k][c][1]=Bneg (after clip to [0,1])
    // pk = A; nk = (1-A)*Bneg; w = pk-nk; bias = sum_k nk; den = sum_k (pk+nk)
    float w[CC][KK], bias[CC], invden[CC];
#pragma unroll
    for (int c = 0; c < CC; ++c) {
        float nsum = 0.f, dsum = 0.f;
#pragma unroll
        for (int k = 0; k < KK; ++k) {
            float a = reas[k * (CC * 2) + c * 2 + 0];
            float b = reas[k * (CC * 2) + c * 2 + 1];
            a = fminf(fmaxf(a, 0.f), 1.f);
            b = fminf(fmaxf(b, 0.f), 1.f);
            float nk = (1.f - a) * b;
            w[c][k] = a - nk;
            nsum += nk;
            dsum += a + nk;
        }
        bias[c] = nsum;
        invden[c] = 1.f / dsum;
    }

    const float4* x4 = (const float4*)x;

    for (int row = wave_global; row < B; row += n_waves) {
        float acc[KK];
#pragma unroll
        for (int k = 0; k < KK; ++k) acc[k] = 0.f;

#pragma unroll
        for (int j = 0; j < F4_PER_LANE; ++j) {
            float4 xv = x4[(size_t)row * F4_PER_ROW + j * 64 + lane];
#pragma unroll
            for (int k = 0; k < KK; ++k) {
                float dx = xv.x - cf[k][j].x;
                float dy = xv.y - cf[k][j].y;
                float dz = xv.z - cf[k][j].z;
                float dw = xv.w - cf[k][j].w;
                acc[k] += dx * dx;
                acc[k] += dy * dy;
                acc[k] += dz * dz;
                acc[k] += dw * dw;
            }
        }

        // butterfly reduction across the 64-lane wave: all lanes end with full d2[k]
#pragma unroll
        for (int k = 0; k < KK; ++k) {
#pragma unroll
            for (int off = 32; off > 0; off >>= 1)
                acc[k] += __shfl_xor(acc[k], off, 64);
        }

        float sims[KK];
#pragma unroll
        for (int k = 0; k < KK; ++k)
            sims[k] = __expf(-0.5f * acc[k]);   // variance = 1

        if (lane < CC) {
            const int c = lane;
            float num = bias[c];
#pragma unroll
            for (int k = 0; k < KK; ++k) num += sims[k] * w[c][k];
            out[(size_t)row * CC + c] = num * invden[c];
        }
    }
}

extern "C" void kernel_launch(void* const* d_in, const int* in_sizes, int n_in,
                              void* d_out, int out_size, void* d_ws, size_t ws_size,
                              hipStream_t stream) {
    const float* x = (const float*)d_in[0];
    const float* comps = (const float*)d_in[1];
    const float* reas = (const float*)d_in[2];
    float* out = (float*)d_out;
    const int B = in_sizes[0] / DD;   // 32768

    // 1024 blocks x 256 threads = 4096 waves -> 8 rows per wave (grid-stride).
    const int blocks = 1024;
    cbc_kernel<<<blocks, 256, 0, stream>>>(x, comps, reas, out, B);
}